// Round 2
// baseline (1004.652 us; speedup 1.0000x reference)
//
#include <hip/hip_runtime.h>

#define N_NODES 50000
#define N_EDGES 1000000
#define N_ETYPES 3
#define TOT (N_ETYPES * N_NODES)   // 150000 (etype,node) bins
#define NB 782                     // ceil(50000/64) buckets of 64 dst nodes
#define TOTB (N_ETYPES * NB)       // 2346 bucket bins

typedef _Float16 f16x8 __attribute__((ext_vector_type(8)));
typedef float f32x4 __attribute__((ext_vector_type(4)));

// ---------- Kernel 0a: W[e][k][n] fp32 -> Wt[e][n][k] fp16 ----------
__global__ void k_prep_w(const float* __restrict__ W, _Float16* __restrict__ Wt) {
    int e  = blockIdx.y;
    int id = blockIdx.x * blockDim.x + threadIdx.x;   // 0..32767
    int k  = id >> 7;
    int n  = id & 127;
    Wt[(size_t)e * 32768 + (size_t)n * 256 + k] =
        (_Float16)W[(size_t)e * 32768 + (size_t)k * 128 + n];
}

// ---------- Kernel 0b: x fp32 -> fp16 (read once instead of 3x in gemm) ----------
__global__ void k_prep_x(const float* __restrict__ x, _Float16* __restrict__ x16) {
    int id = blockIdx.x * blockDim.x + threadIdx.x;   // 0..1599999 (exact)
    const float* p = x + (size_t)id * 8;
    f32x4 lo = *(const f32x4*)p;
    f32x4 hi = *(const f32x4*)(p + 4);
    f16x8 v;
    #pragma unroll
    for (int j = 0; j < 4; ++j) {
        v[j]     = (_Float16)lo[j];
        v[j + 4] = (_Float16)hi[j];
    }
    *(f16x8*)(x16 + (size_t)id * 8) = v;
}

// ---------- Kernel 1: Wh[e] = fp16( x @ W[e] + b[e] )  (MFMA, no LDS) ----------
// A-fragments now load straight from fp16 x16 (16B loads, no cvt chain).
// Fragment maps (m89/m91-verified; verified bit-identical vs scalar GEMM in the
// earlier session): A[m=lane&15][k=quad*8+j], B^T row = lane&15,
// D: col=lane&15, row=quad*4+reg.
__global__ __launch_bounds__(256) void k_gemm(
    const _Float16* __restrict__ x16,        // [N,256] fp16
    const _Float16* __restrict__ Wt,         // [3][128][256] fp16 (W^T)
    const float* __restrict__ b,             // [3][128] fp32
    unsigned short* __restrict__ Wh)         // [3][N][128] fp16 bits
{
    const int e    = blockIdx.y;
    const int tid  = threadIdx.x;
    const int lane = tid & 63;
    const int w    = tid >> 6;       // wave 0..3
    const int q    = lane >> 4;      // quad 0..3
    const int c    = lane & 15;      // m for A, n for B/D
    const int rowBase = blockIdx.x * 256;
    const _Float16* Bt = Wt + (size_t)e * 32768;   // [128][256]

    f32x4 acc[4][8];
    #pragma unroll
    for (int mt = 0; mt < 4; ++mt)
        #pragma unroll
        for (int nt = 0; nt < 8; ++nt)
            acc[mt][nt] = (f32x4){0.f, 0.f, 0.f, 0.f};

    int arow[4];
    #pragma unroll
    for (int mt = 0; mt < 4; ++mt) {
        int r = rowBase + w * 64 + mt * 16 + c;
        arow[mt] = (r < N_NODES) ? r : (N_NODES - 1);   // clamp; discarded at store
    }

    #pragma unroll
    for (int ks = 0; ks < 8; ++ks) {           // K = 256 = 8 * 32
        f16x8 afrag[4];
        #pragma unroll
        for (int mt = 0; mt < 4; ++mt)
            afrag[mt] = *(const f16x8*)(x16 + (size_t)arow[mt] * 256 + ks * 32 + q * 8);
        #pragma unroll
        for (int nt = 0; nt < 8; ++nt) {
            f16x8 bfrag = *(const f16x8*)(Bt + (size_t)(nt * 16 + c) * 256 + ks * 32 + q * 8);
            #pragma unroll
            for (int mt = 0; mt < 4; ++mt)
                acc[mt][nt] = __builtin_amdgcn_mfma_f32_16x16x32_f16(
                    afrag[mt], bfrag, acc[mt][nt], 0, 0, 0);
        }
    }

    const size_t whBase = (size_t)e * N_NODES * 128;
    #pragma unroll
    for (int nt = 0; nt < 8; ++nt) {
        float bias = b[e * 128 + nt * 16 + c];
        #pragma unroll
        for (int mt = 0; mt < 4; ++mt) {
            int baseRow = rowBase + w * 64 + mt * 16 + q * 4;
            #pragma unroll
            for (int r = 0; r < 4; ++r) {
                int row = baseRow + r;
                if (row < N_NODES) {
                    float v = acc[mt][nt][r] + bias;
                    Wh[whBase + (size_t)row * 128 + nt * 16 + c] =
                        __builtin_bit_cast(unsigned short, (_Float16)v);
                }
            }
        }
    }
}

// ---------- Bucket-level histogram (LDS-aggregated) ----------
__global__ __launch_bounds__(256) void k_hist_b(const int* __restrict__ dst,
                                                int* __restrict__ cnt_b) {
    __shared__ int lcnt[NB];
    int e = blockIdx.y;
    for (int j = threadIdx.x; j < NB; j += 256) lcnt[j] = 0;
    __syncthreads();
    int beg = blockIdx.x * 8192;
    int end = beg + 8192; if (end > N_EDGES) end = N_EDGES;
    const int* de = dst + (size_t)e * N_EDGES;
    for (int i = beg + threadIdx.x; i < end; i += 256)
        atomicAdd(&lcnt[de[i] >> 6], 1);
    __syncthreads();
    for (int j = threadIdx.x; j < NB; j += 256) {
        int c = lcnt[j];
        if (c) atomicAdd(&cnt_b[e * NB + j], c);
    }
}

// ---------- scan (length-parameterized; verified structure from prev round) ----------
__global__ __launch_bounds__(1024) void k_scan1(const int* __restrict__ cnt,
                                                int* __restrict__ local,
                                                int* __restrict__ partials, int len) {
    int gid = blockIdx.x * 1024 + threadIdx.x;
    int v = (gid < len) ? cnt[gid] : 0;
    int lane = threadIdx.x & 63;
    int wv = threadIdx.x >> 6;
    int s = v;
    #pragma unroll
    for (int d = 1; d < 64; d <<= 1) {
        int t = __shfl_up(s, d);
        if (lane >= d) s += t;
    }
    __shared__ int wsum[16];
    __shared__ int woff[16];
    if (lane == 63) wsum[wv] = s;
    __syncthreads();
    if (threadIdx.x == 0) {
        int a = 0;
        #pragma unroll
        for (int i = 0; i < 16; ++i) { int t = wsum[i]; woff[i] = a; a += t; }
        partials[blockIdx.x] = a;
    }
    __syncthreads();
    int excl = s - v + woff[wv];
    if (gid < len) local[gid] = excl;
}

__global__ __launch_bounds__(256) void k_scan2(int* __restrict__ partials, int nb) {
    int tid = threadIdx.x;
    int v = (tid < nb) ? partials[tid] : 0;
    int lane = tid & 63, wv = tid >> 6;
    int s = v;
    #pragma unroll
    for (int d = 1; d < 64; d <<= 1) {
        int t = __shfl_up(s, d);
        if (lane >= d) s += t;
    }
    __shared__ int wsum[4];
    __shared__ int woff[4];
    if (lane == 63) wsum[wv] = s;
    __syncthreads();
    if (tid == 0) {
        int a = 0;
        #pragma unroll
        for (int i = 0; i < 4; ++i) { int t = wsum[i]; woff[i] = a; a += t; }
    }
    __syncthreads();
    int excl = s - v + woff[wv];
    if (tid < nb) partials[tid] = excl;
}

__global__ void k_scan3(int* __restrict__ local, const int* __restrict__ partials,
                        int* __restrict__ cursor, int len) {
    int gid = blockIdx.x * blockDim.x + threadIdx.x;
    if (gid >= len) return;
    int o = local[gid] + partials[gid >> 10];
    local[gid] = o;
    cursor[gid] = o;
}

// ---------- Bucket fill: packed (src | dstlow<<16) records ----------
// Active write window = 2346 bucket tails * 128B ~ 300KB -> L2-resident,
// lines fill before eviction -> ~12MB HBM writes instead of 203MB.
__global__ void k_fill_b(const int* __restrict__ src, const int* __restrict__ dst,
                         int* __restrict__ gcur, unsigned* __restrict__ grec) {
    int e = blockIdx.y;
    int i = blockIdx.x * blockDim.x + threadIdx.x;
    if (i >= N_EDGES) return;
    int s = src[(size_t)e * N_EDGES + i];
    int d = dst[(size_t)e * N_EDGES + i];
    int pos = atomicAdd(&gcur[e * NB + (d >> 6)], 1);
    grec[pos] = (unsigned)s | ((unsigned)(d & 63) << 16);
}

// ---------- Per-bucket record list -> exact per-node CSR (LDS only) ----------
__global__ __launch_bounds__(256) void k_csr_b(
    const int* __restrict__ offs_b, const int* __restrict__ cnt_b,
    const unsigned* __restrict__ grec,
    int* __restrict__ offs, int* __restrict__ cnt, int* __restrict__ nbr)
{
    __shared__ int ndeg[64];
    __shared__ int ncur[64];
    int e = blockIdx.y, bx = blockIdx.x;
    int eb = e * NB + bx;
    int beg = offs_b[eb];
    int m   = cnt_b[eb];
    int tid = threadIdx.x;
    if (tid < 64) ndeg[tid] = 0;
    __syncthreads();
    for (int i = tid; i < m; i += 256)
        atomicAdd(&ndeg[grec[beg + i] >> 16], 1);
    __syncthreads();
    if (tid < 64) {                     // wave 0: exclusive scan of 64 degrees
        int v = ndeg[tid];
        int s = v;
        #pragma unroll
        for (int d = 1; d < 64; d <<= 1) {
            int t = __shfl_up(s, d);
            if (tid >= d) s += t;
        }
        int excl = s - v;
        ncur[tid] = excl;
        int node = bx * 64 + tid;
        if (node < N_NODES) {
            cnt [e * N_NODES + node] = v;
            offs[e * N_NODES + node] = beg + excl;
        }
    }
    __syncthreads();
    for (int i = tid; i < m; i += 256) {
        unsigned r = grec[beg + i];
        int p = atomicAdd(&ncur[r >> 16], 1);
        nbr[beg + p] = (int)(r & 0xFFFFu);   // src fits in 16 bits (50000 < 65536)
    }
}

// ---------- Gather: one wave per (etype,node); mean + transpose fused ----------
__global__ __launch_bounds__(256) void k_gather(
    const int* __restrict__ offs, const int* __restrict__ cnt,
    const int* __restrict__ nbr, const unsigned short* __restrict__ Wh,
    float* __restrict__ out)
{
    const int lane = threadIdx.x & 63;
    int wid = blockIdx.x * (blockDim.x >> 6) + (threadIdx.x >> 6);
    if (wid >= TOT) return;
    int e = wid / N_NODES;
    int n = wid - e * N_NODES;
    int beg = offs[wid];
    int d   = cnt[wid];
    int end = beg + d;
    const unsigned* base = (const unsigned*)Wh + (size_t)e * N_NODES * 64; // 64 u32/row
    float a0 = 0.f, a1 = 0.f;
    for (int c0 = beg; c0 < end; c0 += 64) {
        int m = end - c0; if (m > 64) m = 64;
        int idx = (c0 + lane < end) ? nbr[c0 + lane] : 0;   // prefetch ids
        for (int j = 0; j < m; ++j) {
            int s = __shfl(idx, j);
            unsigned u = base[(size_t)s * 64 + lane];
            a0 += (float)__builtin_bit_cast(_Float16, (unsigned short)(u & 0xFFFFu));
            a1 += (float)__builtin_bit_cast(_Float16, (unsigned short)(u >> 16));
        }
    }
    float inv = (d > 0) ? (1.0f / (float)d) : 0.f;
    float2 o;
    o.x = a0 * inv;
    o.y = a1 * inv;
    *(float2*)(out + (size_t)n * 384 + e * 128 + 2 * lane) = o;
}

// ---------- launch ----------
extern "C" void kernel_launch(void* const* d_in, const int* in_sizes, int n_in,
                              void* d_out, int out_size, void* d_ws, size_t ws_size,
                              hipStream_t stream) {
    const float* x    = (const float*)d_in[0];
    const int*   esrc = (const int*)d_in[1];
    const int*   edst = (const int*)d_in[2];
    const float* W    = (const float*)d_in[3];
    const float* bias = (const float*)d_in[4];
    float*       out  = (float*)d_out;            // fp32 output [N,3,128]

    char* ws = (char*)d_ws;
    _Float16*       Wt  = (_Float16*)ws;                          //    196,608 B
    _Float16*       x16 = (_Float16*)(ws + 196608);               // 25,600,000 B
    unsigned short* Wh  = (unsigned short*)(ws + 25796608);       // 38,400,000 B
    unsigned* grec = (unsigned*)(ws + 64196608);                  // 12,000,000 B
    int* nbr       = (int*)(ws + 76196608);                       // 12,000,000 B
    int* offs      = (int*)(ws + 88196608);                       //    600,000 B
    int* cnt       = (int*)(ws + 88796608);                       //    600,000 B
    int* cnt_b     = (int*)(ws + 89396608);                       //      9,472 B
    int* offs_b    = (int*)(ws + 89406080);                       //      9,472 B
    int* gcur      = (int*)(ws + 89415552);                       //      9,472 B
    int* partials  = (int*)(ws + 89425024);                       //      4,096 B

    hipMemsetAsync(cnt_b, 0, TOTB * sizeof(int), stream);

    k_prep_w<<<dim3(128, 3), 256, 0, stream>>>(W, Wt);
    k_prep_x<<<6250, 256, 0, stream>>>(x, x16);
    k_gemm<<<dim3(196, 3), 256, 0, stream>>>(x16, Wt, bias, Wh);

    const int EB  = (N_EDGES + 255) / 256;           // 3907
    const int HB  = (N_EDGES + 8191) / 8192;         // 123
    k_hist_b<<<dim3(HB, 3), 256, 0, stream>>>(edst, cnt_b);
    const int SB = (TOTB + 1023) / 1024;             // 3
    k_scan1<<<SB, 1024, 0, stream>>>(cnt_b, offs_b, partials, TOTB);
    k_scan2<<<1, 256, 0, stream>>>(partials, SB);
    k_scan3<<<(TOTB + 255) / 256, 256, 0, stream>>>(offs_b, partials, gcur, TOTB);
    k_fill_b<<<dim3(EB, 3), 256, 0, stream>>>(esrc, edst, gcur, grec);
    k_csr_b<<<dim3(NB, 3), 256, 0, stream>>>(offs_b, cnt_b, grec, offs, cnt, nbr);

    k_gather<<<(TOT + 3) / 4, 256, 0, stream>>>(offs, cnt, nbr, Wh, out);
}

// Round 3
// 473.046 us; speedup vs baseline: 2.1238x; 2.1238x over previous
//
#include <hip/hip_runtime.h>

#define N_NODES 50000
#define N_EDGES 1000000
#define N_ETYPES 3
#define TOT (N_ETYPES * N_NODES)   // 150000 (etype,node) bins
#define NB 782                     // ceil(50000/64) buckets of 64 dst nodes
#define TOTB (N_ETYPES * NB)       // 2346 bucket bins
#define EPB 8192                   // edges per fill block
#define EPT 32                     // edges per thread (EPB/256)

typedef _Float16 f16x8 __attribute__((ext_vector_type(8)));
typedef float f32x4 __attribute__((ext_vector_type(4)));

// ---------- Kernel 0a: W[e][k][n] fp32 -> Wt[e][n][k] fp16 ----------
__global__ void k_prep_w(const float* __restrict__ W, _Float16* __restrict__ Wt) {
    int e  = blockIdx.y;
    int id = blockIdx.x * blockDim.x + threadIdx.x;   // 0..32767
    int k  = id >> 7;
    int n  = id & 127;
    Wt[(size_t)e * 32768 + (size_t)n * 256 + k] =
        (_Float16)W[(size_t)e * 32768 + (size_t)k * 128 + n];
}

// ---------- Kernel 0b: x fp32 -> fp16 (read once instead of 3x in gemm) ----------
__global__ void k_prep_x(const float* __restrict__ x, _Float16* __restrict__ x16) {
    int id = blockIdx.x * blockDim.x + threadIdx.x;   // 0..1599999 (exact)
    const float* p = x + (size_t)id * 8;
    f32x4 lo = *(const f32x4*)p;
    f32x4 hi = *(const f32x4*)(p + 4);
    f16x8 v;
    #pragma unroll
    for (int j = 0; j < 4; ++j) {
        v[j]     = (_Float16)lo[j];
        v[j + 4] = (_Float16)hi[j];
    }
    *(f16x8*)(x16 + (size_t)id * 8) = v;
}

// ---------- Kernel 1: Wh[e] = fp16( x @ W[e] + b[e] )  (MFMA, no LDS) ----------
// Fragment maps (m89/m91-verified; verified bit-identical vs scalar GEMM):
//   A[m=lane&15][k=quad*8+j], B^T row = lane&15, D: col=lane&15, row=quad*4+reg.
__global__ __launch_bounds__(256) void k_gemm(
    const _Float16* __restrict__ x16,        // [N,256] fp16
    const _Float16* __restrict__ Wt,         // [3][128][256] fp16 (W^T)
    const float* __restrict__ b,             // [3][128] fp32
    unsigned short* __restrict__ Wh)         // [3][N][128] fp16 bits
{
    const int e    = blockIdx.y;
    const int tid  = threadIdx.x;
    const int lane = tid & 63;
    const int w    = tid >> 6;       // wave 0..3
    const int q    = lane >> 4;      // quad 0..3
    const int c    = lane & 15;      // m for A, n for B/D
    const int rowBase = blockIdx.x * 256;
    const _Float16* Bt = Wt + (size_t)e * 32768;   // [128][256]

    f32x4 acc[4][8];
    #pragma unroll
    for (int mt = 0; mt < 4; ++mt)
        #pragma unroll
        for (int nt = 0; nt < 8; ++nt)
            acc[mt][nt] = (f32x4){0.f, 0.f, 0.f, 0.f};

    int arow[4];
    #pragma unroll
    for (int mt = 0; mt < 4; ++mt) {
        int r = rowBase + w * 64 + mt * 16 + c;
        arow[mt] = (r < N_NODES) ? r : (N_NODES - 1);   // clamp; discarded at store
    }

    #pragma unroll
    for (int ks = 0; ks < 8; ++ks) {           // K = 256 = 8 * 32
        f16x8 afrag[4];
        #pragma unroll
        for (int mt = 0; mt < 4; ++mt)
            afrag[mt] = *(const f16x8*)(x16 + (size_t)arow[mt] * 256 + ks * 32 + q * 8);
        #pragma unroll
        for (int nt = 0; nt < 8; ++nt) {
            f16x8 bfrag = *(const f16x8*)(Bt + (size_t)(nt * 16 + c) * 256 + ks * 32 + q * 8);
            #pragma unroll
            for (int mt = 0; mt < 4; ++mt)
                acc[mt][nt] = __builtin_amdgcn_mfma_f32_16x16x32_f16(
                    afrag[mt], bfrag, acc[mt][nt], 0, 0, 0);
        }
    }

    const size_t whBase = (size_t)e * N_NODES * 128;
    #pragma unroll
    for (int nt = 0; nt < 8; ++nt) {
        float bias = b[e * 128 + nt * 16 + c];
        #pragma unroll
        for (int mt = 0; mt < 4; ++mt) {
            int baseRow = rowBase + w * 64 + mt * 16 + q * 4;
            #pragma unroll
            for (int r = 0; r < 4; ++r) {
                int row = baseRow + r;
                if (row < N_NODES) {
                    float v = acc[mt][nt][r] + bias;
                    Wh[whBase + (size_t)row * 128 + nt * 16 + c] =
                        __builtin_bit_cast(unsigned short, (_Float16)v);
                }
            }
        }
    }
}

// ---------- Bucket-level histogram (LDS-aggregated) ----------
__global__ __launch_bounds__(256) void k_hist_b(const int* __restrict__ dst,
                                                int* __restrict__ cnt_b) {
    __shared__ int lcnt[NB];
    int e = blockIdx.y;
    for (int j = threadIdx.x; j < NB; j += 256) lcnt[j] = 0;
    __syncthreads();
    int beg = blockIdx.x * EPB;
    int end = beg + EPB; if (end > N_EDGES) end = N_EDGES;
    const int* de = dst + (size_t)e * N_EDGES;
    for (int i = beg + threadIdx.x; i < end; i += 256)
        atomicAdd(&lcnt[de[i] >> 6], 1);
    __syncthreads();
    for (int j = threadIdx.x; j < NB; j += 256) {
        int c = lcnt[j];
        if (c) atomicAdd(&cnt_b[e * NB + j], c);
    }
}

// ---------- scan (length-parameterized) ----------
__global__ __launch_bounds__(1024) void k_scan1(const int* __restrict__ cnt,
                                                int* __restrict__ local,
                                                int* __restrict__ partials, int len) {
    int gid = blockIdx.x * 1024 + threadIdx.x;
    int v = (gid < len) ? cnt[gid] : 0;
    int lane = threadIdx.x & 63;
    int wv = threadIdx.x >> 6;
    int s = v;
    #pragma unroll
    for (int d = 1; d < 64; d <<= 1) {
        int t = __shfl_up(s, d);
        if (lane >= d) s += t;
    }
    __shared__ int wsum[16];
    __shared__ int woff[16];
    if (lane == 63) wsum[wv] = s;
    __syncthreads();
    if (threadIdx.x == 0) {
        int a = 0;
        #pragma unroll
        for (int i = 0; i < 16; ++i) { int t = wsum[i]; woff[i] = a; a += t; }
        partials[blockIdx.x] = a;
    }
    __syncthreads();
    int excl = s - v + woff[wv];
    if (gid < len) local[gid] = excl;
}

__global__ __launch_bounds__(256) void k_scan2(int* __restrict__ partials, int nb) {
    int tid = threadIdx.x;
    int v = (tid < nb) ? partials[tid] : 0;
    int lane = tid & 63, wv = tid >> 6;
    int s = v;
    #pragma unroll
    for (int d = 1; d < 64; d <<= 1) {
        int t = __shfl_up(s, d);
        if (lane >= d) s += t;
    }
    __shared__ int wsum[4];
    __shared__ int woff[4];
    if (lane == 63) wsum[wv] = s;
    __syncthreads();
    if (tid == 0) {
        int a = 0;
        #pragma unroll
        for (int i = 0; i < 4; ++i) { int t = wsum[i]; woff[i] = a; a += t; }
    }
    __syncthreads();
    int excl = s - v + woff[wv];
    if (tid < nb) partials[tid] = excl;
}

__global__ void k_scan3(int* __restrict__ local, const int* __restrict__ partials,
                        int* __restrict__ cursor, int len) {
    int gid = blockIdx.x * blockDim.x + threadIdx.x;
    if (gid >= len) return;
    int o = local[gid] + partials[gid >> 10];
    local[gid] = o;
    cursor[gid] = o;
}

// ---------- Bucket fill, LDS-aggregated ----------
// Round-2 post-mortem: per-edge global atomics on 2346 cursors = 1280-deep
// same-address RMW chains (~450ns each) = 575us. This version: per-edge LDS
// atomics (block-private, contention ~10), ONE global atomicAdd per
// (block,bucket) to reserve a range (chain depth 123), then positioned writes.
// Writes stay bucket-grouped -> L2-resident tails -> no write amplification.
__global__ __launch_bounds__(256) void k_fill_b(
    const int* __restrict__ src, const int* __restrict__ dst,
    int* __restrict__ gcur, unsigned* __restrict__ grec)
{
    __shared__ int lcnt[NB];
    __shared__ int lbase[NB];
    const int e   = blockIdx.y;
    const int tid = threadIdx.x;
    const int beg = blockIdx.x * EPB;
    const int* se = src + (size_t)e * N_EDGES;
    const int* de = dst + (size_t)e * N_EDGES;

    for (int j = tid; j < NB; j += 256) lcnt[j] = 0;
    __syncthreads();

    unsigned rec[EPT];
    int      bl [EPT];
    #pragma unroll
    for (int k = 0; k < EPT; ++k) {
        int i = beg + k * 256 + tid;           // coalesced
        if (i < N_EDGES) {
            int s = se[i];
            int d = de[i];
            int b = d >> 6;
            int lpos = atomicAdd(&lcnt[b], 1);
            rec[k] = (unsigned)s | ((unsigned)(d & 63) << 16);
            bl[k]  = b | (lpos << 10);         // b<1024 (10b), lpos<8192 (13b)
        } else {
            bl[k] = -1;
        }
    }
    __syncthreads();
    for (int j = tid; j < NB; j += 256) {
        int c = lcnt[j];
        lbase[j] = c ? atomicAdd(&gcur[e * NB + j], c) : 0;
    }
    __syncthreads();
    #pragma unroll
    for (int k = 0; k < EPT; ++k) {
        if (bl[k] >= 0) {
            int b    = bl[k] & 1023;
            int lpos = bl[k] >> 10;
            grec[lbase[b] + lpos] = rec[k];
        }
    }
}

// ---------- Per-bucket record list -> exact per-node CSR (LDS only) ----------
__global__ __launch_bounds__(256) void k_csr_b(
    const int* __restrict__ offs_b, const int* __restrict__ cnt_b,
    const unsigned* __restrict__ grec,
    int* __restrict__ offs, int* __restrict__ cnt, int* __restrict__ nbr)
{
    __shared__ int ndeg[64];
    __shared__ int ncur[64];
    int e = blockIdx.y, bx = blockIdx.x;
    int eb = e * NB + bx;
    int beg = offs_b[eb];
    int m   = cnt_b[eb];
    int tid = threadIdx.x;
    if (tid < 64) ndeg[tid] = 0;
    __syncthreads();
    for (int i = tid; i < m; i += 256)
        atomicAdd(&ndeg[grec[beg + i] >> 16], 1);
    __syncthreads();
    if (tid < 64) {                     // wave 0: exclusive scan of 64 degrees
        int v = ndeg[tid];
        int s = v;
        #pragma unroll
        for (int d = 1; d < 64; d <<= 1) {
            int t = __shfl_up(s, d);
            if (tid >= d) s += t;
        }
        int excl = s - v;
        ncur[tid] = excl;
        int node = bx * 64 + tid;
        if (node < N_NODES) {
            cnt [e * N_NODES + node] = v;
            offs[e * N_NODES + node] = beg + excl;
        }
    }
    __syncthreads();
    for (int i = tid; i < m; i += 256) {
        unsigned r = grec[beg + i];
        int p = atomicAdd(&ncur[r >> 16], 1);
        nbr[beg + p] = (int)(r & 0xFFFFu);   // src fits in 16 bits (50000 < 65536)
    }
}

// ---------- Gather: one wave per (etype,node); mean + transpose fused ----------
__global__ __launch_bounds__(256) void k_gather(
    const int* __restrict__ offs, const int* __restrict__ cnt,
    const int* __restrict__ nbr, const unsigned short* __restrict__ Wh,
    float* __restrict__ out)
{
    const int lane = threadIdx.x & 63;
    int wid = blockIdx.x * (blockDim.x >> 6) + (threadIdx.x >> 6);
    if (wid >= TOT) return;
    int e = wid / N_NODES;
    int n = wid - e * N_NODES;
    int beg = offs[wid];
    int d   = cnt[wid];
    int end = beg + d;
    const unsigned* base = (const unsigned*)Wh + (size_t)e * N_NODES * 64; // 64 u32/row
    float a0 = 0.f, a1 = 0.f;
    for (int c0 = beg; c0 < end; c0 += 64) {
        int m = end - c0; if (m > 64) m = 64;
        int idx = (c0 + lane < end) ? nbr[c0 + lane] : 0;   // prefetch ids
        for (int j = 0; j < m; ++j) {
            int s = __shfl(idx, j);
            unsigned u = base[(size_t)s * 64 + lane];
            a0 += (float)__builtin_bit_cast(_Float16, (unsigned short)(u & 0xFFFFu));
            a1 += (float)__builtin_bit_cast(_Float16, (unsigned short)(u >> 16));
        }
    }
    float inv = (d > 0) ? (1.0f / (float)d) : 0.f;
    float2 o;
    o.x = a0 * inv;
    o.y = a1 * inv;
    *(float2*)(out + (size_t)n * 384 + e * 128 + 2 * lane) = o;
}

// ---------- launch ----------
extern "C" void kernel_launch(void* const* d_in, const int* in_sizes, int n_in,
                              void* d_out, int out_size, void* d_ws, size_t ws_size,
                              hipStream_t stream) {
    const float* x    = (const float*)d_in[0];
    const int*   esrc = (const int*)d_in[1];
    const int*   edst = (const int*)d_in[2];
    const float* W    = (const float*)d_in[3];
    const float* bias = (const float*)d_in[4];
    float*       out  = (float*)d_out;            // fp32 output [N,3,128]

    char* ws = (char*)d_ws;
    _Float16*       Wt  = (_Float16*)ws;                          //    196,608 B
    _Float16*       x16 = (_Float16*)(ws + 196608);               // 25,600,000 B
    unsigned short* Wh  = (unsigned short*)(ws + 25796608);       // 38,400,000 B
    unsigned* grec = (unsigned*)(ws + 64196608);                  // 12,000,000 B
    int* nbr       = (int*)(ws + 76196608);                       // 12,000,000 B
    int* offs      = (int*)(ws + 88196608);                       //    600,000 B
    int* cnt       = (int*)(ws + 88796608);                       //    600,000 B
    int* cnt_b     = (int*)(ws + 89396608);                       //      9,472 B
    int* offs_b    = (int*)(ws + 89406080);                       //      9,472 B
    int* gcur      = (int*)(ws + 89415552);                       //      9,472 B
    int* partials  = (int*)(ws + 89425024);                       //      4,096 B

    hipMemsetAsync(cnt_b, 0, TOTB * sizeof(int), stream);

    k_prep_w<<<dim3(128, 3), 256, 0, stream>>>(W, Wt);
    k_prep_x<<<6250, 256, 0, stream>>>(x, x16);
    k_gemm<<<dim3(196, 3), 256, 0, stream>>>(x16, Wt, bias, Wh);

    const int FB = (N_EDGES + EPB - 1) / EPB;        // 123
    k_hist_b<<<dim3(FB, 3), 256, 0, stream>>>(edst, cnt_b);
    const int SB = (TOTB + 1023) / 1024;             // 3
    k_scan1<<<SB, 1024, 0, stream>>>(cnt_b, offs_b, partials, TOTB);
    k_scan2<<<1, 256, 0, stream>>>(partials, SB);
    k_scan3<<<(TOTB + 255) / 256, 256, 0, stream>>>(offs_b, partials, gcur, TOTB);
    k_fill_b<<<dim3(FB, 3), 256, 0, stream>>>(esrc, edst, gcur, grec);
    k_csr_b<<<dim3(NB, 3), 256, 0, stream>>>(offs_b, cnt_b, grec, offs, cnt, nbr);

    k_gather<<<(TOT + 3) / 4, 256, 0, stream>>>(offs, cnt, nbr, Wh, out);
}

// Round 4
// 383.380 us; speedup vs baseline: 2.6205x; 1.2339x over previous
//
#include <hip/hip_runtime.h>

#define N_NODES 50000
#define N_EDGES 1000000
#define N_ETYPES 3
#define TOT (N_ETYPES * N_NODES)   // 150000 (etype,node) bins
#define NB 782                     // ceil(50000/64) buckets of 64 dst nodes
#define TOTB (N_ETYPES * NB)       // 2346 bucket bins
#define EPB 8192                   // edges per fill block
#define EPT 32                     // edges per thread (EPB/256)

typedef _Float16 f16x8 __attribute__((ext_vector_type(8)));
typedef float f32x4 __attribute__((ext_vector_type(4)));

// ---------- Kernel 0a: W[e][k][n] fp32 -> Wt[e][n][k] fp16 ----------
__global__ void k_prep_w(const float* __restrict__ W, _Float16* __restrict__ Wt) {
    int e  = blockIdx.y;
    int id = blockIdx.x * blockDim.x + threadIdx.x;   // 0..32767
    int k  = id >> 7;
    int n  = id & 127;
    Wt[(size_t)e * 32768 + (size_t)n * 256 + k] =
        (_Float16)W[(size_t)e * 32768 + (size_t)k * 128 + n];
}

// ---------- Kernel 0b: x fp32 -> fp16 (read once instead of 3x in gemm) ----------
__global__ void k_prep_x(const float* __restrict__ x, _Float16* __restrict__ x16) {
    int id = blockIdx.x * blockDim.x + threadIdx.x;   // 0..1599999 (exact)
    const float* p = x + (size_t)id * 8;
    f32x4 lo = *(const f32x4*)p;
    f32x4 hi = *(const f32x4*)(p + 4);
    f16x8 v;
    #pragma unroll
    for (int j = 0; j < 4; ++j) {
        v[j]     = (_Float16)lo[j];
        v[j + 4] = (_Float16)hi[j];
    }
    *(f16x8*)(x16 + (size_t)id * 8) = v;
}

// ---------- Kernel 1: Wh[e] = fp16( x @ W[e] + b[e] )  (MFMA, no LDS) ----------
// Fragment maps (m89/m91-verified; verified bit-identical vs scalar GEMM):
//   A[m=lane&15][k=quad*8+j], B^T row = lane&15, D: col=lane&15, row=quad*4+reg.
__global__ __launch_bounds__(256) void k_gemm(
    const _Float16* __restrict__ x16,        // [N,256] fp16
    const _Float16* __restrict__ Wt,         // [3][128][256] fp16 (W^T)
    const float* __restrict__ b,             // [3][128] fp32
    unsigned short* __restrict__ Wh)         // [3][N][128] fp16 bits
{
    const int e    = blockIdx.y;
    const int tid  = threadIdx.x;
    const int lane = tid & 63;
    const int w    = tid >> 6;       // wave 0..3
    const int q    = lane >> 4;      // quad 0..3
    const int c    = lane & 15;      // m for A, n for B/D
    const int rowBase = blockIdx.x * 256;
    const _Float16* Bt = Wt + (size_t)e * 32768;   // [128][256]

    f32x4 acc[4][8];
    #pragma unroll
    for (int mt = 0; mt < 4; ++mt)
        #pragma unroll
        for (int nt = 0; nt < 8; ++nt)
            acc[mt][nt] = (f32x4){0.f, 0.f, 0.f, 0.f};

    int arow[4];
    #pragma unroll
    for (int mt = 0; mt < 4; ++mt) {
        int r = rowBase + w * 64 + mt * 16 + c;
        arow[mt] = (r < N_NODES) ? r : (N_NODES - 1);   // clamp; discarded at store
    }

    #pragma unroll
    for (int ks = 0; ks < 8; ++ks) {           // K = 256 = 8 * 32
        f16x8 afrag[4];
        #pragma unroll
        for (int mt = 0; mt < 4; ++mt)
            afrag[mt] = *(const f16x8*)(x16 + (size_t)arow[mt] * 256 + ks * 32 + q * 8);
        #pragma unroll
        for (int nt = 0; nt < 8; ++nt) {
            f16x8 bfrag = *(const f16x8*)(Bt + (size_t)(nt * 16 + c) * 256 + ks * 32 + q * 8);
            #pragma unroll
            for (int mt = 0; mt < 4; ++mt)
                acc[mt][nt] = __builtin_amdgcn_mfma_f32_16x16x32_f16(
                    afrag[mt], bfrag, acc[mt][nt], 0, 0, 0);
        }
    }

    const size_t whBase = (size_t)e * N_NODES * 128;
    #pragma unroll
    for (int nt = 0; nt < 8; ++nt) {
        float bias = b[e * 128 + nt * 16 + c];
        #pragma unroll
        for (int mt = 0; mt < 4; ++mt) {
            int baseRow = rowBase + w * 64 + mt * 16 + q * 4;
            #pragma unroll
            for (int r = 0; r < 4; ++r) {
                int row = baseRow + r;
                if (row < N_NODES) {
                    float v = acc[mt][nt][r] + bias;
                    Wh[whBase + (size_t)row * 128 + nt * 16 + c] =
                        __builtin_bit_cast(unsigned short, (_Float16)v);
                }
            }
        }
    }
}

// ---------- Bucket-level histogram (LDS-aggregated) ----------
__global__ __launch_bounds__(256) void k_hist_b(const int* __restrict__ dst,
                                                int* __restrict__ cnt_b) {
    __shared__ int lcnt[NB];
    int e = blockIdx.y;
    for (int j = threadIdx.x; j < NB; j += 256) lcnt[j] = 0;
    __syncthreads();
    int beg = blockIdx.x * EPB;
    int end = beg + EPB; if (end > N_EDGES) end = N_EDGES;
    const int* de = dst + (size_t)e * N_EDGES;
    for (int i = beg + threadIdx.x; i < end; i += 256)
        atomicAdd(&lcnt[de[i] >> 6], 1);
    __syncthreads();
    for (int j = threadIdx.x; j < NB; j += 256) {
        int c = lcnt[j];
        if (c) atomicAdd(&cnt_b[e * NB + j], c);
    }
}

// ---------- scan (length-parameterized) ----------
__global__ __launch_bounds__(1024) void k_scan1(const int* __restrict__ cnt,
                                                int* __restrict__ local,
                                                int* __restrict__ partials, int len) {
    int gid = blockIdx.x * 1024 + threadIdx.x;
    int v = (gid < len) ? cnt[gid] : 0;
    int lane = threadIdx.x & 63;
    int wv = threadIdx.x >> 6;
    int s = v;
    #pragma unroll
    for (int d = 1; d < 64; d <<= 1) {
        int t = __shfl_up(s, d);
        if (lane >= d) s += t;
    }
    __shared__ int wsum[16];
    __shared__ int woff[16];
    if (lane == 63) wsum[wv] = s;
    __syncthreads();
    if (threadIdx.x == 0) {
        int a = 0;
        #pragma unroll
        for (int i = 0; i < 16; ++i) { int t = wsum[i]; woff[i] = a; a += t; }
        partials[blockIdx.x] = a;
    }
    __syncthreads();
    int excl = s - v + woff[wv];
    if (gid < len) local[gid] = excl;
}

__global__ __launch_bounds__(256) void k_scan2(int* __restrict__ partials, int nb) {
    int tid = threadIdx.x;
    int v = (tid < nb) ? partials[tid] : 0;
    int lane = tid & 63, wv = tid >> 6;
    int s = v;
    #pragma unroll
    for (int d = 1; d < 64; d <<= 1) {
        int t = __shfl_up(s, d);
        if (lane >= d) s += t;
    }
    __shared__ int wsum[4];
    __shared__ int woff[4];
    if (lane == 63) wsum[wv] = s;
    __syncthreads();
    if (tid == 0) {
        int a = 0;
        #pragma unroll
        for (int i = 0; i < 4; ++i) { int t = wsum[i]; woff[i] = a; a += t; }
    }
    __syncthreads();
    int excl = s - v + woff[wv];
    if (tid < nb) partials[tid] = excl;
}

__global__ void k_scan3(int* __restrict__ local, const int* __restrict__ partials,
                        int* __restrict__ cursor, int len) {
    int gid = blockIdx.x * blockDim.x + threadIdx.x;
    if (gid >= len) return;
    int o = local[gid] + partials[gid >> 10];
    local[gid] = o;
    cursor[gid] = o;
}

// ---------- Bucket fill, LDS-aggregated ----------
// Per-edge LDS atomics (block-private), ONE global atomicAdd per (block,bucket)
// to reserve a range, then positioned writes. Bucket-grouped -> L2-resident
// tails -> no write amplification; global atomic chain depth = #blocks (123).
__global__ __launch_bounds__(256) void k_fill_b(
    const int* __restrict__ src, const int* __restrict__ dst,
    int* __restrict__ gcur, unsigned* __restrict__ grec)
{
    __shared__ int lcnt[NB];
    __shared__ int lbase[NB];
    const int e   = blockIdx.y;
    const int tid = threadIdx.x;
    const int beg = blockIdx.x * EPB;
    const int* se = src + (size_t)e * N_EDGES;
    const int* de = dst + (size_t)e * N_EDGES;

    for (int j = tid; j < NB; j += 256) lcnt[j] = 0;
    __syncthreads();

    unsigned rec[EPT];
    int      bl [EPT];
    #pragma unroll
    for (int k = 0; k < EPT; ++k) {
        int i = beg + k * 256 + tid;           // coalesced
        if (i < N_EDGES) {
            int s = se[i];
            int d = de[i];
            int b = d >> 6;
            int lpos = atomicAdd(&lcnt[b], 1);
            rec[k] = (unsigned)s | ((unsigned)(d & 63) << 16);
            bl[k]  = b | (lpos << 10);         // b<1024 (10b), lpos<8192 (13b)
        } else {
            bl[k] = -1;
        }
    }
    __syncthreads();
    for (int j = tid; j < NB; j += 256) {
        int c = lcnt[j];
        lbase[j] = c ? atomicAdd(&gcur[e * NB + j], c) : 0;
    }
    __syncthreads();
    #pragma unroll
    for (int k = 0; k < EPT; ++k) {
        if (bl[k] >= 0) {
            int b    = bl[k] & 1023;
            int lpos = bl[k] >> 10;
            grec[lbase[b] + lpos] = rec[k];
        }
    }
}

// ---------- Per-bucket record list -> exact per-node CSR (LDS only) ----------
__global__ __launch_bounds__(256) void k_csr_b(
    const int* __restrict__ offs_b, const int* __restrict__ cnt_b,
    const unsigned* __restrict__ grec,
    int* __restrict__ offs, int* __restrict__ cnt, int* __restrict__ nbr)
{
    __shared__ int ndeg[64];
    __shared__ int ncur[64];
    int e = blockIdx.y, bx = blockIdx.x;
    int eb = e * NB + bx;
    int beg = offs_b[eb];
    int m   = cnt_b[eb];
    int tid = threadIdx.x;
    if (tid < 64) ndeg[tid] = 0;
    __syncthreads();
    for (int i = tid; i < m; i += 256)
        atomicAdd(&ndeg[grec[beg + i] >> 16], 1);
    __syncthreads();
    if (tid < 64) {                     // wave 0: exclusive scan of 64 degrees
        int v = ndeg[tid];
        int s = v;
        #pragma unroll
        for (int d = 1; d < 64; d <<= 1) {
            int t = __shfl_up(s, d);
            if (tid >= d) s += t;
        }
        int excl = s - v;
        ncur[tid] = excl;
        int node = bx * 64 + tid;
        if (node < N_NODES) {
            cnt [e * N_NODES + node] = v;
            offs[e * N_NODES + node] = beg + excl;
        }
    }
    __syncthreads();
    for (int i = tid; i < m; i += 256) {
        unsigned r = grec[beg + i];
        int p = atomicAdd(&ncur[r >> 16], 1);
        nbr[beg + p] = (int)(r & 0xFFFFu);   // src fits in 16 bits (50000 < 65536)
    }
}

// ---------- Gather: one wave per (etype,node); mean + transpose fused ----------
// Round-3 post-mortem: 185us latency-bound (MLP=1: one dependent row-load in
// flight per wave; FETCH 289MB at only 2TB/s, VALU 31%). Fix: 8 independent
// row-loads in flight (explicit unroll; readlane keeps addresses SGPR-based),
// masked 8-wide tail so short neighbor lists don't re-serialize.
__global__ __launch_bounds__(256) void k_gather(
    const int* __restrict__ offs, const int* __restrict__ cnt,
    const int* __restrict__ nbr, const unsigned short* __restrict__ Wh,
    float* __restrict__ out)
{
    const int lane = threadIdx.x & 63;
    int wid = blockIdx.x * (blockDim.x >> 6) + (threadIdx.x >> 6);
    if (wid >= TOT) return;
    int e = wid / N_NODES;
    int n = wid - e * N_NODES;
    int beg = offs[wid];
    int d   = cnt[wid];
    int end = beg + d;
    const unsigned* base = (const unsigned*)Wh + (size_t)e * N_NODES * 64; // 64 u32/row
    float a0 = 0.f, a1 = 0.f;
    for (int c0 = beg; c0 < end; c0 += 64) {
        int m = end - c0; if (m > 64) m = 64;
        int idx = (c0 + lane < end) ? nbr[c0 + lane] : 0;   // chunk's neighbor ids
        int j = 0;
        for (; j + 8 <= m; j += 8) {            // 8 independent loads in flight
            unsigned u[8];
            #pragma unroll
            for (int k = 0; k < 8; ++k) {
                int s = __builtin_amdgcn_readlane(idx, j + k);   // uniform -> SGPR
                u[k] = base[(size_t)s * 64 + lane];
            }
            #pragma unroll
            for (int k = 0; k < 8; ++k) {
                a0 += (float)__builtin_bit_cast(_Float16, (unsigned short)(u[k] & 0xFFFFu));
                a1 += (float)__builtin_bit_cast(_Float16, (unsigned short)(u[k] >> 16));
            }
        }
        if (j < m) {                            // masked 8-wide tail
            unsigned u[8];
            #pragma unroll
            for (int k = 0; k < 8; ++k) {
                int jj = j + k;
                int js = (jj < m) ? jj : 0;     // uniform clamp (s_cselect)
                int s = __builtin_amdgcn_readlane(idx, js);
                u[k] = base[(size_t)s * 64 + lane];
            }
            #pragma unroll
            for (int k = 0; k < 8; ++k) {
                if (j + k < m) {
                    a0 += (float)__builtin_bit_cast(_Float16, (unsigned short)(u[k] & 0xFFFFu));
                    a1 += (float)__builtin_bit_cast(_Float16, (unsigned short)(u[k] >> 16));
                }
            }
        }
    }
    float inv = (d > 0) ? (1.0f / (float)d) : 0.f;
    float2 o;
    o.x = a0 * inv;
    o.y = a1 * inv;
    *(float2*)(out + (size_t)n * 384 + e * 128 + 2 * lane) = o;
}

// ---------- launch ----------
extern "C" void kernel_launch(void* const* d_in, const int* in_sizes, int n_in,
                              void* d_out, int out_size, void* d_ws, size_t ws_size,
                              hipStream_t stream) {
    const float* x    = (const float*)d_in[0];
    const int*   esrc = (const int*)d_in[1];
    const int*   edst = (const int*)d_in[2];
    const float* W    = (const float*)d_in[3];
    const float* bias = (const float*)d_in[4];
    float*       out  = (float*)d_out;            // fp32 output [N,3,128]

    char* ws = (char*)d_ws;
    _Float16*       Wt  = (_Float16*)ws;                          //    196,608 B
    _Float16*       x16 = (_Float16*)(ws + 196608);               // 25,600,000 B
    unsigned short* Wh  = (unsigned short*)(ws + 25796608);       // 38,400,000 B
    unsigned* grec = (unsigned*)(ws + 64196608);                  // 12,000,000 B
    int* nbr       = (int*)(ws + 76196608);                       // 12,000,000 B
    int* offs      = (int*)(ws + 88196608);                       //    600,000 B
    int* cnt       = (int*)(ws + 88796608);                       //    600,000 B
    int* cnt_b     = (int*)(ws + 89396608);                       //      9,472 B
    int* offs_b    = (int*)(ws + 89406080);                       //      9,472 B
    int* gcur      = (int*)(ws + 89415552);                       //      9,472 B
    int* partials  = (int*)(ws + 89425024);                       //      4,096 B

    hipMemsetAsync(cnt_b, 0, TOTB * sizeof(int), stream);

    k_prep_w<<<dim3(128, 3), 256, 0, stream>>>(W, Wt);
    k_prep_x<<<6250, 256, 0, stream>>>(x, x16);
    k_gemm<<<dim3(196, 3), 256, 0, stream>>>(x16, Wt, bias, Wh);

    const int FB = (N_EDGES + EPB - 1) / EPB;        // 123
    k_hist_b<<<dim3(FB, 3), 256, 0, stream>>>(edst, cnt_b);
    const int SB = (TOTB + 1023) / 1024;             // 3
    k_scan1<<<SB, 1024, 0, stream>>>(cnt_b, offs_b, partials, TOTB);
    k_scan2<<<1, 256, 0, stream>>>(partials, SB);
    k_scan3<<<(TOTB + 255) / 256, 256, 0, stream>>>(offs_b, partials, gcur, TOTB);
    k_fill_b<<<dim3(FB, 3), 256, 0, stream>>>(esrc, edst, gcur, grec);
    k_csr_b<<<dim3(NB, 3), 256, 0, stream>>>(offs_b, cnt_b, grec, offs, cnt, nbr);

    k_gather<<<(TOT + 3) / 4, 256, 0, stream>>>(offs, cnt, nbr, Wh, out);
}